// Round 9
// baseline (305.429 us; speedup 1.0000x reference)
//
#include <hip/hip_runtime.h>

// ATTRIBUTION PROBE ROUND: R5 config, proj launched 3x (idempotent) to
// measure T_proj = (total - 176us)/2 against the R5 baseline.

// Problem constants (from reference)
constexpr int B  = 8;
constexpr int T  = 256;
constexpr int U1 = 65;
constexpr int DK = 640;   // D_ENC == D_pred
constexpr int V  = 1024;

constexpr int M_ENC  = B * T;    // 2048
constexpr int M_PRED = B * U1;   // 520

constexpr int TM = 16;                              // rows per block tile
constexpr int NB_ENC  = M_ENC / TM;                 // 128
constexpr int NB_PRED = (M_PRED + TM - 1) / TM;     // 33
constexpr int COLSPLIT = 4;                         // 256 cols per block
constexpr int NCOL4 = (V / COLSPLIT) / 4;           // 64 float4 per col-part

typedef float f32x4 __attribute__((ext_vector_type(4)));

__device__ __forceinline__ void fma4(float a, const float4& wv, float4& c) {
    c.x = fmaf(a, wv.x, c.x);
    c.y = fmaf(a, wv.y, c.y);
    c.z = fmaf(a, wv.z, c.z);
    c.w = fmaf(a, wv.w, c.w);
}

// ---------------------------------------------------------------------------
// enc_proj = enc @ W[:640]; pred_proj = pred @ W[640:] + bias
// R5 config: 644 blocks, 256 threads, thread = 4 rows x 1 float4, unroll 2.
// Measured (as part of R5 total): ~176 us with bcast.
// ---------------------------------------------------------------------------
__global__ __launch_bounds__(256) void proj_kernel(
    const float* __restrict__ enc, const float* __restrict__ pred,
    const float* __restrict__ W, const float* __restrict__ bias,
    float* __restrict__ enc_proj, float* __restrict__ pred_proj)
{
    __shared__ float a_s[TM * DK];   // 40 KB

    const int tid      = threadIdx.x;
    const int rowblock = blockIdx.x >> 2;           // which 16-row tile
    const int colpart  = blockIdx.x & 3;            // which 256-col part

    const bool isEnc = (rowblock < NB_ENC);
    const float* A   = isEnc ? enc : pred;
    float* O         = isEnc ? enc_proj : pred_proj;
    const float* Wb  = isEnc ? W : (W + (size_t)DK * V);
    const int M      = isEnc ? M_ENC : M_PRED;
    const int row0   = (isEnc ? rowblock : (rowblock - NB_ENC)) * TM;

    // ---- stage A tile (16 rows x 640 f32) into LDS ----
    {
        const int r  = tid >> 4;                    // row within tile
        const int c0 = tid & 15;                    // f4 lane within row
        const float4* Ag = reinterpret_cast<const float4*>(A + (size_t)row0 * DK);
        float4* As = reinterpret_cast<float4*>(a_s);
        const bool valid = (row0 + r < M);
        #pragma unroll
        for (int k = 0; k < DK / 4 / 16; ++k) {     // 10
            const int i = r * (DK / 4) + c0 + k * 16;
            float4 v = make_float4(0.f, 0.f, 0.f, 0.f);
            if (valid) v = Ag[i];
            As[i] = v;
        }
    }
    __syncthreads();

    const int tx = tid & (NCOL4 - 1);
    const int rg = tid >> 6;                        // wave-uniform

    float4 acc[4];
    #pragma unroll
    for (int r = 0; r < 4; ++r) acc[r] = make_float4(0.f, 0.f, 0.f, 0.f);

    const float4* W4 = reinterpret_cast<const float4*>(Wb)
                       + (size_t)colpart * NCOL4 + tx;

    #pragma unroll 2
    for (int d = 0; d < DK; d += 4) {
        float4 w0 = W4[(size_t)(d + 0) * (V / 4)];
        float4 w1 = W4[(size_t)(d + 1) * (V / 4)];
        float4 w2 = W4[(size_t)(d + 2) * (V / 4)];
        float4 w3 = W4[(size_t)(d + 3) * (V / 4)];
        #pragma unroll
        for (int r = 0; r < 4; ++r) {
            const float4 av = *reinterpret_cast<const float4*>(
                &a_s[(rg * 4 + r) * DK + d]);       // wave-uniform -> LDS broadcast
            fma4(av.x, w0, acc[r]);
            fma4(av.y, w1, acc[r]);
            fma4(av.z, w2, acc[r]);
            fma4(av.w, w3, acc[r]);
        }
    }

    float4 bv = make_float4(0.f, 0.f, 0.f, 0.f);
    if (!isEnc) bv = reinterpret_cast<const float4*>(bias)[colpart * NCOL4 + tx];

    #pragma unroll
    for (int r = 0; r < 4; ++r) {
        const int row = row0 + rg * 4 + r;
        if (row < M) {
            float4 o = acc[r];
            o.x += bv.x; o.y += bv.y; o.z += bv.z; o.w += bv.w;
            reinterpret_cast<float4*>(O)[(size_t)row * (V / 4) + colpart * NCOL4 + tx] = o;
        }
    }
}

// ---------------------------------------------------------------------------
// out[b,t,u,v] = enc_proj[b,t,v] + pred_proj[b,u,v]
// ---------------------------------------------------------------------------
__global__ __launch_bounds__(256) void bcast_kernel(
    const float* __restrict__ enc_proj, const float* __restrict__ pred_proj,
    float* __restrict__ out)
{
    const int bt  = blockIdx.x;          // 0..2047
    const int b   = bt >> 8;             // T = 256
    const int tid = threadIdx.x;

    const f32x4* e4 = reinterpret_cast<const f32x4*>(enc_proj) + (size_t)bt * (V / 4);
    const f32x4* p4 = reinterpret_cast<const f32x4*>(pred_proj) + (size_t)b * U1 * (V / 4);
    f32x4* o4       = reinterpret_cast<f32x4*>(out) + (size_t)bt * U1 * (V / 4);

    const f32x4 e = e4[tid];

    #pragma unroll 4
    for (int u = 0; u < U1; ++u) {
        f32x4 p = p4[(size_t)u * (V / 4) + tid];
        f32x4 o = e + p;
        __builtin_nontemporal_store(o, &o4[(size_t)u * (V / 4) + tid]);
    }
}

extern "C" void kernel_launch(void* const* d_in, const int* in_sizes, int n_in,
                              void* d_out, int out_size, void* d_ws, size_t ws_size,
                              hipStream_t stream)
{
    const float* enc  = (const float*)d_in[0];   // (8,256,640)
    const float* pred = (const float*)d_in[1];   // (8,65,640)
    const float* W    = (const float*)d_in[2];   // (1280,1024)
    const float* bias = (const float*)d_in[3];   // (1024,)
    float* out = (float*)d_out;                  // (8,256,65,1024)

    float* enc_proj  = (float*)d_ws;                         // 8 MiB
    float* pred_proj = enc_proj + (size_t)M_ENC * V;         // 2.1 MiB

    // PROBE: launch proj 3x (idempotent). total = T_bcast + 3*T_proj.
    proj_kernel<<<(NB_ENC + NB_PRED) * COLSPLIT, 256, 0, stream>>>(
        enc, pred, W, bias, enc_proj, pred_proj);
    proj_kernel<<<(NB_ENC + NB_PRED) * COLSPLIT, 256, 0, stream>>>(
        enc, pred, W, bias, enc_proj, pred_proj);
    proj_kernel<<<(NB_ENC + NB_PRED) * COLSPLIT, 256, 0, stream>>>(
        enc, pred, W, bias, enc_proj, pred_proj);

    bcast_kernel<<<M_ENC, 256, 0, stream>>>(enc_proj, pred_proj, out);
}

// Round 10
// 174.829 us; speedup vs baseline: 1.7470x; 1.7470x over previous
//
#include <hip/hip_runtime.h>

// Problem constants (from reference)
constexpr int B  = 8;
constexpr int T  = 256;
constexpr int U1 = 65;
constexpr int DK = 640;    // D_ENC == D_pred
constexpr int V  = 1024;
constexpr int KTOT = 2 * DK;  // 1280 (enc k in [0,640), pred k in [640,1280))

constexpr int M_ENC  = B * T;    // 2048
constexpr int M_PRED = B * U1;   // 520

typedef float  f32x4  __attribute__((ext_vector_type(4)));
typedef short  short8 __attribute__((ext_vector_type(8)));
typedef unsigned short u16x4 __attribute__((ext_vector_type(4)));

// f32 -> bf16 bits, round-to-nearest-even
__device__ __forceinline__ short f2bf(float f) {
    union { float f; unsigned u; } x; x.f = f;
    unsigned r = x.u + 0x7fffu + ((x.u >> 16) & 1u);
    return (short)(r >> 16);
}
// bf16 bits -> f32
__device__ __forceinline__ float bf2f(unsigned short s) {
    union { unsigned u; float f; } x; x.u = ((unsigned)s) << 16;
    return x.f;
}

// ---------------------------------------------------------------------------
// Wt[v][k] = bf16(W[k][v]).  Grid: 4 v-blocks x 10 k-chunks = 40 blocks x 256.
// Loads coalesced (consecutive tid -> consecutive v); stores 16B/thread.
// ---------------------------------------------------------------------------
__global__ __launch_bounds__(256) void wt_kernel(
    const float* __restrict__ W, short* __restrict__ Wt)
{
    const int vb = blockIdx.x & 3;
    const int kb = blockIdx.x >> 2;
    const int v  = vb * 256 + threadIdx.x;
    const int k0 = kb * 128;

    for (int k = k0; k < k0 + 128; k += 8) {
        short8 s;
        #pragma unroll
        for (int j = 0; j < 8; ++j)
            s[j] = f2bf(W[(size_t)(k + j) * V + v]);
        *reinterpret_cast<short8*>(Wt + (size_t)v * KTOT + k) = s;
    }
}

// ---------------------------------------------------------------------------
// MFMA proj: enc_proj = bf16(enc @ We), pred_proj = bf16(pred @ Wp + bias).
// Block = 128 thr (2 waves), block tile 64x128, wave tile 64x64.
// 16x16x32 bf16 MFMA, LDS-free: A-frags f32->bf16 in-register from L2,
// B-frags contiguous 16B from Wt. A/B loaded with the SAME (g,j)->k map,
// so the k-permutation inside the instruction cancels; C/D layout per
// HW-verified mapping col=lane&15, row=(lane>>4)*4+reg.
// ---------------------------------------------------------------------------
constexpr int BM = 64, BN = 128;
constexpr int GBE_R = M_ENC / BM;              // 32
constexpr int GB_C  = V / BN;                  // 8
constexpr int NBE   = GBE_R * GB_C;            // 256
constexpr int GBP_R = (M_PRED + BM - 1) / BM;  // 9
constexpr int NBP   = GBP_R * GB_C;            // 72

__global__ __launch_bounds__(128) void mfma_proj_kernel(
    const float* __restrict__ enc, const float* __restrict__ pred,
    const short* __restrict__ Wt, const float* __restrict__ bias,
    short* __restrict__ enc_proj, short* __restrict__ pred_proj)
{
    const int bid   = blockIdx.x;
    const bool isEnc = (bid < NBE);
    const int lb    = isEnc ? bid : bid - NBE;
    const int rb    = lb >> 3;                 // / GB_C
    const int cb    = lb & 7;

    const float* A = isEnc ? enc : pred;
    short* O       = isEnc ? enc_proj : pred_proj;
    const int M    = isEnc ? M_ENC : M_PRED;
    const int kofs = isEnc ? 0 : DK;

    const int wid  = threadIdx.x >> 6;         // wave id 0/1
    const int lane = threadIdx.x & 63;
    const int m    = lane & 15;
    const int g    = lane >> 4;                // 0..3

    const int row0 = rb * BM;
    const int col0 = cb * BN + wid * 64;

    f32x4 z4; z4[0] = z4[1] = z4[2] = z4[3] = 0.f;
    f32x4 acc[4][4];
    #pragma unroll
    for (int mt = 0; mt < 4; ++mt)
        #pragma unroll
        for (int nt = 0; nt < 4; ++nt) acc[mt][nt] = z4;

    for (int kk = 0; kk < DK; kk += 32) {
        const int k0 = kk + g * 8;
        short8 a[4], b[4];
        #pragma unroll
        for (int mt = 0; mt < 4; ++mt) {
            const int row = row0 + mt * 16 + m;
            short8 s;
            if (row < M) {
                const float* p = A + (size_t)row * DK + k0;
                const f32x4 x = *reinterpret_cast<const f32x4*>(p);
                const f32x4 y = *reinterpret_cast<const f32x4*>(p + 4);
                s[0] = f2bf(x[0]); s[1] = f2bf(x[1]);
                s[2] = f2bf(x[2]); s[3] = f2bf(x[3]);
                s[4] = f2bf(y[0]); s[5] = f2bf(y[1]);
                s[6] = f2bf(y[2]); s[7] = f2bf(y[3]);
            } else {
                #pragma unroll
                for (int j = 0; j < 8; ++j) s[j] = 0;
            }
            a[mt] = s;
        }
        #pragma unroll
        for (int nt = 0; nt < 4; ++nt) {
            const int v = col0 + nt * 16 + m;
            b[nt] = *reinterpret_cast<const short8*>(
                Wt + (size_t)v * KTOT + kofs + k0);
        }
        #pragma unroll
        for (int mt = 0; mt < 4; ++mt)
            #pragma unroll
            for (int nt = 0; nt < 4; ++nt)
                acc[mt][nt] = __builtin_amdgcn_mfma_f32_16x16x32_bf16(
                    a[mt], b[nt], acc[mt][nt], 0, 0, 0);
    }

    // epilogue: bias for pred, f32 -> bf16 store
    #pragma unroll
    for (int nt = 0; nt < 4; ++nt) {
        const int col = col0 + nt * 16 + m;
        const float bv = isEnc ? 0.f : bias[col];
        #pragma unroll
        for (int mt = 0; mt < 4; ++mt) {
            #pragma unroll
            for (int q = 0; q < 4; ++q) {
                const int row = row0 + mt * 16 + g * 4 + q;
                if (row < M)
                    O[(size_t)row * V + col] = f2bf(acc[mt][nt][q] + bv);
            }
        }
    }
}

// ---------------------------------------------------------------------------
// out[b,t,u,v] = enc_proj[b,t,v] + pred_proj[b,u,v]   (bf16 inputs, f32 out)
// Grid: 2048 blocks x 256; thread owns 4 cols. Structure identical to R5.
// ---------------------------------------------------------------------------
__global__ __launch_bounds__(256) void bcast_kernel(
    const short* __restrict__ enc_proj, const short* __restrict__ pred_proj,
    float* __restrict__ out)
{
    const int bt  = blockIdx.x;          // 0..2047
    const int b   = bt >> 8;             // T = 256
    const int tid = threadIdx.x;

    const u16x4 ev = *reinterpret_cast<const u16x4*>(
        enc_proj + (size_t)bt * V + tid * 4);
    f32x4 e;
    e[0] = bf2f(ev[0]); e[1] = bf2f(ev[1]); e[2] = bf2f(ev[2]); e[3] = bf2f(ev[3]);

    const short* p = pred_proj + (size_t)b * U1 * V + tid * 4;
    f32x4* o4 = reinterpret_cast<f32x4*>(out + (size_t)bt * U1 * V) + tid;

    #pragma unroll 4
    for (int u = 0; u < U1; ++u) {
        const u16x4 pv = *reinterpret_cast<const u16x4*>(p + (size_t)u * V);
        f32x4 pf;
        pf[0] = bf2f(pv[0]); pf[1] = bf2f(pv[1]);
        pf[2] = bf2f(pv[2]); pf[3] = bf2f(pv[3]);
        const f32x4 o = e + pf;
        __builtin_nontemporal_store(o, &o4[(size_t)u * (V / 4)]);
    }
}

extern "C" void kernel_launch(void* const* d_in, const int* in_sizes, int n_in,
                              void* d_out, int out_size, void* d_ws, size_t ws_size,
                              hipStream_t stream)
{
    const float* enc  = (const float*)d_in[0];   // (8,256,640)
    const float* pred = (const float*)d_in[1];   // (8,65,640)
    const float* W    = (const float*)d_in[2];   // (1280,1024)
    const float* bias = (const float*)d_in[3];   // (1024,)
    float* out = (float*)d_out;                  // (8,256,65,1024)

    // ws layout (bf16/short elements): Wt | enc_proj | pred_proj  = 7.9 MB
    short* Wt        = (short*)d_ws;                         // 1024*1280
    short* enc_proj  = Wt + (size_t)V * KTOT;                // 2048*1024
    short* pred_proj = enc_proj + (size_t)M_ENC * V;         // 520*1024

    wt_kernel<<<40, 256, 0, stream>>>(W, Wt);
    mfma_proj_kernel<<<NBE + NBP, 128, 0, stream>>>(
        enc, pred, Wt, bias, enc_proj, pred_proj);
    bcast_kernel<<<M_ENC, 256, 0, stream>>>(enc_proj, pred_proj, out);
}

// Round 11
// 158.948 us; speedup vs baseline: 1.9216x; 1.0999x over previous
//
#include <hip/hip_runtime.h>

// Problem constants (from reference)
constexpr int B  = 8;
constexpr int T  = 256;
constexpr int U1 = 65;
constexpr int DK = 640;    // D_ENC == D_pred
constexpr int V  = 1024;
constexpr int KTOT = 2 * DK;  // 1280

constexpr int M_ENC  = B * T;    // 2048
constexpr int M_PRED = B * U1;   // 520

typedef float  f32x4  __attribute__((ext_vector_type(4)));
typedef short  short8 __attribute__((ext_vector_type(8)));
typedef unsigned short u16x4 __attribute__((ext_vector_type(4)));

__device__ __forceinline__ short f2bf(float f) {
    union { float f; unsigned u; } x; x.f = f;
    unsigned r = x.u + 0x7fffu + ((x.u >> 16) & 1u);
    return (short)(r >> 16);
}
__device__ __forceinline__ f32x4 bf4_to_f32(u16x4 s) {
    f32x4 o;
    union { unsigned u; float f; } x;
    x.u = ((unsigned)s[0]) << 16; o[0] = x.f;
    x.u = ((unsigned)s[1]) << 16; o[1] = x.f;
    x.u = ((unsigned)s[2]) << 16; o[2] = x.f;
    x.u = ((unsigned)s[3]) << 16; o[3] = x.f;
    return o;
}

// ---------------------------------------------------------------------------
// prep: Wt[v][k]=bf16(W[k][v]); enc_bf=bf16(enc); pred_bf=bf16(pred).
// Grid: 40 (Wt) + 640 (enc) + 163 (pred) = 843 blocks x 256.
// ---------------------------------------------------------------------------
constexpr int ENC_ELEM8  = M_ENC * DK / 8;    // 163840
constexpr int PRED_ELEM8 = M_PRED * DK / 8;   // 41600
constexpr int NB_WT   = 40;
constexpr int NB_ENCC = ENC_ELEM8 / 256;      // 640
constexpr int NB_PREDC = (PRED_ELEM8 + 255) / 256;  // 163

__global__ __launch_bounds__(256) void prep_kernel(
    const float* __restrict__ W, const float* __restrict__ enc,
    const float* __restrict__ pred, short* __restrict__ Wt,
    short* __restrict__ enc_bf, short* __restrict__ pred_bf)
{
    const int bid = blockIdx.x;
    const int tid = threadIdx.x;

    if (bid < NB_WT) {
        // W transpose+convert: vb = 256-col group, kb = 128-k chunk
        const int vb = bid & 3;
        const int kb = bid >> 2;
        const int v  = vb * 256 + tid;
        const int k0 = kb * 128;
        for (int k = k0; k < k0 + 128; k += 8) {
            short8 s;
            #pragma unroll
            for (int j = 0; j < 8; ++j)
                s[j] = f2bf(W[(size_t)(k + j) * V + v]);
            *reinterpret_cast<short8*>(Wt + (size_t)v * KTOT + k) = s;
        }
    } else if (bid < NB_WT + NB_ENCC) {
        const int idx  = (bid - NB_WT) * 256 + tid;
        const size_t e = (size_t)idx * 8;
        const f32x4 x = *reinterpret_cast<const f32x4*>(enc + e);
        const f32x4 y = *reinterpret_cast<const f32x4*>(enc + e + 4);
        short8 s;
        s[0]=f2bf(x[0]); s[1]=f2bf(x[1]); s[2]=f2bf(x[2]); s[3]=f2bf(x[3]);
        s[4]=f2bf(y[0]); s[5]=f2bf(y[1]); s[6]=f2bf(y[2]); s[7]=f2bf(y[3]);
        *reinterpret_cast<short8*>(enc_bf + e) = s;
    } else {
        const int idx = (bid - NB_WT - NB_ENCC) * 256 + tid;
        if (idx < PRED_ELEM8) {
            const size_t e = (size_t)idx * 8;
            const f32x4 x = *reinterpret_cast<const f32x4*>(pred + e);
            const f32x4 y = *reinterpret_cast<const f32x4*>(pred + e + 4);
            short8 s;
            s[0]=f2bf(x[0]); s[1]=f2bf(x[1]); s[2]=f2bf(x[2]); s[3]=f2bf(x[3]);
            s[4]=f2bf(y[0]); s[5]=f2bf(y[1]); s[6]=f2bf(y[2]); s[7]=f2bf(y[3]);
            *reinterpret_cast<short8*>(pred_bf + e) = s;
        }
    }
}

// ---------------------------------------------------------------------------
// GEMM: O = bf16(Abf @ Wt[:, kofs:kofs+640] (+bias)).  Pure bf16 MFMA.
// Block = 256 thr (4 waves, 2x2), block tile 64x64, wave tile 32x32.
// Per k-step per wave: 4 x 16B loads + 4 MFMAs (1:1), zero conversions.
// Grid: rowTiles x 16. enc: 512 blocks; pred: 144.
// A/B use the SAME (g,j)->k map (k0 = kk + g*8, 8 contiguous), so the
// MFMA-internal k-permutation cancels; C/D: col=lane&15, row=(lane>>4)*4+q.
// ---------------------------------------------------------------------------
__global__ __launch_bounds__(256) void gemm_kernel(
    const short* __restrict__ Abf, const short* __restrict__ Wt,
    const float* __restrict__ bias, short* __restrict__ O,
    int M, int kofs)
{
    const int rb   = blockIdx.x >> 4;
    const int cb   = blockIdx.x & 15;
    const int wid  = threadIdx.x >> 6;
    const int lane = threadIdx.x & 63;
    const int wr   = wid >> 1, wc = wid & 1;
    const int m    = lane & 15, g = lane >> 4;

    const int row0 = rb * 64 + wr * 32;
    const int col0 = cb * 64 + wc * 32;

    f32x4 z4; z4[0]=z4[1]=z4[2]=z4[3]=0.f;
    f32x4 acc00 = z4, acc01 = z4, acc10 = z4, acc11 = z4;

    const bool v0 = (row0 + m) < M;
    const bool v1 = (row0 + 16 + m) < M;
    const short* a0p = Abf + (size_t)(row0 + m) * DK;
    const short* a1p = Abf + (size_t)(row0 + 16 + m) * DK;
    const short* b0p = Wt + (size_t)(col0 + m) * KTOT + kofs;
    const short* b1p = Wt + (size_t)(col0 + 16 + m) * KTOT + kofs;

    short8 zero8;
    #pragma unroll
    for (int j = 0; j < 8; ++j) zero8[j] = 0;

    #pragma unroll 2
    for (int kk = 0; kk < DK; kk += 32) {
        const int k0 = kk + g * 8;
        const short8 a0 = v0 ? *reinterpret_cast<const short8*>(a0p + k0) : zero8;
        const short8 a1 = v1 ? *reinterpret_cast<const short8*>(a1p + k0) : zero8;
        const short8 b0 = *reinterpret_cast<const short8*>(b0p + k0);
        const short8 b1 = *reinterpret_cast<const short8*>(b1p + k0);
        acc00 = __builtin_amdgcn_mfma_f32_16x16x32_bf16(a0, b0, acc00, 0, 0, 0);
        acc01 = __builtin_amdgcn_mfma_f32_16x16x32_bf16(a0, b1, acc01, 0, 0, 0);
        acc10 = __builtin_amdgcn_mfma_f32_16x16x32_bf16(a1, b0, acc10, 0, 0, 0);
        acc11 = __builtin_amdgcn_mfma_f32_16x16x32_bf16(a1, b1, acc11, 0, 0, 0);
    }

    #pragma unroll
    for (int nt = 0; nt < 2; ++nt) {
        const int col = col0 + nt * 16 + m;
        const float bv = bias ? bias[col] : 0.f;
        #pragma unroll
        for (int mt = 0; mt < 2; ++mt) {
            const f32x4 a = nt ? (mt ? acc11 : acc01) : (mt ? acc10 : acc00);
            #pragma unroll
            for (int q = 0; q < 4; ++q) {
                const int row = row0 + mt * 16 + g * 4 + q;
                if (row < M)
                    O[(size_t)row * V + col] = f2bf(a[q] + bv);
            }
        }
    }
}

// ---------------------------------------------------------------------------
// out[bt][u][v] = enc_proj[bt][v] + pred_proj[b][u][v]  (bf16 in, f32 out)
// 2 bt-rows per block (shared p-load -> 32B stored per 8B load), explicit
// 8-deep load batches for MLP. Grid: 1024 blocks x 256 thr.
// ---------------------------------------------------------------------------
__global__ __launch_bounds__(256) void bcast_kernel(
    const short* __restrict__ enc_proj, const short* __restrict__ pred_proj,
    float* __restrict__ out)
{
    const int bt0 = blockIdx.x * 2;
    const int b   = bt0 >> 8;            // T = 256
    const int tid = threadIdx.x;

    const f32x4 e0 = bf4_to_f32(*reinterpret_cast<const u16x4*>(
        enc_proj + (size_t)bt0 * V + tid * 4));
    const f32x4 e1 = bf4_to_f32(*reinterpret_cast<const u16x4*>(
        enc_proj + (size_t)(bt0 + 1) * V + tid * 4));

    const short* p = pred_proj + (size_t)b * U1 * V + tid * 4;
    float* o0 = out + (size_t)bt0 * U1 * V;
    float* o1 = out + (size_t)(bt0 + 1) * U1 * V;

    for (int u0 = 0; u0 < 64; u0 += 8) {
        u16x4 pv[8];
        #pragma unroll
        for (int j = 0; j < 8; ++j)
            pv[j] = *reinterpret_cast<const u16x4*>(p + (size_t)(u0 + j) * V);
        #pragma unroll
        for (int j = 0; j < 8; ++j) {
            const f32x4 pf = bf4_to_f32(pv[j]);
            __builtin_nontemporal_store(e0 + pf,
                reinterpret_cast<f32x4*>(o0 + (size_t)(u0 + j) * V) + tid);
            __builtin_nontemporal_store(e1 + pf,
                reinterpret_cast<f32x4*>(o1 + (size_t)(u0 + j) * V) + tid);
        }
    }
    {   // tail u = 64
        const f32x4 pf = bf4_to_f32(
            *reinterpret_cast<const u16x4*>(p + (size_t)64 * V));
        __builtin_nontemporal_store(e0 + pf,
            reinterpret_cast<f32x4*>(o0 + (size_t)64 * V) + tid);
        __builtin_nontemporal_store(e1 + pf,
            reinterpret_cast<f32x4*>(o1 + (size_t)64 * V) + tid);
    }
}

extern "C" void kernel_launch(void* const* d_in, const int* in_sizes, int n_in,
                              void* d_out, int out_size, void* d_ws, size_t ws_size,
                              hipStream_t stream)
{
    const float* enc  = (const float*)d_in[0];   // (8,256,640)
    const float* pred = (const float*)d_in[1];   // (8,65,640)
    const float* W    = (const float*)d_in[2];   // (1280,1024)
    const float* bias = (const float*)d_in[3];   // (1024,)
    float* out = (float*)d_out;                  // (8,256,65,1024)

    // ws packing (peak 10.10 MB, fits proven >=10.5 MB):
    //   [Wt 2.62MB][encbf/pred_proj 2.62MB][pred_bf 0.67MB][enc_proj 4.19MB]
    // enc_bf dies after enc-GEMM; pred_proj reuses its space.
    short* Wt        = (short*)d_ws;                          // V*KTOT
    short* enc_bf    = Wt + (size_t)V * KTOT;                 // M_ENC*DK
    short* pred_bf   = enc_bf + (size_t)M_ENC * DK;           // M_PRED*DK
    short* enc_proj  = pred_bf + (size_t)M_PRED * DK;         // M_ENC*V
    short* pred_proj = enc_bf;                                // M_PRED*V (reuse)

    prep_kernel<<<NB_WT + NB_ENCC + NB_PREDC, 256, 0, stream>>>(
        W, enc, pred, Wt, enc_bf, pred_bf);

    // enc GEMM: 32 row-tiles x 16 col-tiles = 512 blocks
    gemm_kernel<<<(M_ENC / 64) * 16, 256, 0, stream>>>(
        enc_bf, Wt, nullptr, enc_proj, M_ENC, 0);

    // pred GEMM: 9 x 16 = 144 blocks (writes into enc_bf's dead space)
    gemm_kernel<<<((M_PRED + 63) / 64) * 16, 256, 0, stream>>>(
        pred_bf, Wt, bias, pred_proj, M_PRED, DK);

    bcast_kernel<<<M_ENC / 2, 256, 0, stream>>>(enc_proj, pred_proj, out);
}

// Round 12
// 157.517 us; speedup vs baseline: 1.9390x; 1.0091x over previous
//
#include <hip/hip_runtime.h>

// Problem constants (from reference)
constexpr int B  = 8;
constexpr int T  = 256;
constexpr int U1 = 65;
constexpr int DK = 640;    // D_ENC == D_pred
constexpr int V  = 1024;
constexpr int KTOT = 2 * DK;  // 1280

constexpr int M_ENC  = B * T;    // 2048
constexpr int M_PRED = B * U1;   // 520

typedef float  f32x4  __attribute__((ext_vector_type(4)));
typedef short  short8 __attribute__((ext_vector_type(8)));
typedef unsigned short u16x4 __attribute__((ext_vector_type(4)));

__device__ __forceinline__ short f2bf(float f) {
    union { float f; unsigned u; } x; x.f = f;
    unsigned r = x.u + 0x7fffu + ((x.u >> 16) & 1u);
    return (short)(r >> 16);
}
__device__ __forceinline__ f32x4 bf4_to_f32(u16x4 s) {
    f32x4 o;
    union { unsigned u; float f; } x;
    x.u = ((unsigned)s[0]) << 16; o[0] = x.f;
    x.u = ((unsigned)s[1]) << 16; o[1] = x.f;
    x.u = ((unsigned)s[2]) << 16; o[2] = x.f;
    x.u = ((unsigned)s[3]) << 16; o[3] = x.f;
    return o;
}

// ---------------------------------------------------------------------------
// prep: Wt[v][k]=bf16(W[k][v]); enc_bf=bf16(enc); pred_bf=bf16(pred).
// ---------------------------------------------------------------------------
constexpr int ENC_ELEM8  = M_ENC * DK / 8;    // 163840
constexpr int PRED_ELEM8 = M_PRED * DK / 8;   // 41600
constexpr int NB_WT   = 40;
constexpr int NB_ENCC = ENC_ELEM8 / 256;      // 640
constexpr int NB_PREDC = (PRED_ELEM8 + 255) / 256;  // 163

__global__ __launch_bounds__(256) void prep_kernel(
    const float* __restrict__ W, const float* __restrict__ enc,
    const float* __restrict__ pred, short* __restrict__ Wt,
    short* __restrict__ enc_bf, short* __restrict__ pred_bf)
{
    const int bid = blockIdx.x;
    const int tid = threadIdx.x;

    if (bid < NB_WT) {
        const int vb = bid & 3;
        const int kb = bid >> 2;
        const int v  = vb * 256 + tid;
        const int k0 = kb * 128;
        for (int k = k0; k < k0 + 128; k += 8) {
            short8 s;
            #pragma unroll
            for (int j = 0; j < 8; ++j)
                s[j] = f2bf(W[(size_t)(k + j) * V + v]);
            *reinterpret_cast<short8*>(Wt + (size_t)v * KTOT + k) = s;
        }
    } else if (bid < NB_WT + NB_ENCC) {
        const int idx  = (bid - NB_WT) * 256 + tid;
        const size_t e = (size_t)idx * 8;
        const f32x4 x = *reinterpret_cast<const f32x4*>(enc + e);
        const f32x4 y = *reinterpret_cast<const f32x4*>(enc + e + 4);
        short8 s;
        s[0]=f2bf(x[0]); s[1]=f2bf(x[1]); s[2]=f2bf(x[2]); s[3]=f2bf(x[3]);
        s[4]=f2bf(y[0]); s[5]=f2bf(y[1]); s[6]=f2bf(y[2]); s[7]=f2bf(y[3]);
        *reinterpret_cast<short8*>(enc_bf + e) = s;
    } else {
        const int idx = (bid - NB_WT - NB_ENCC) * 256 + tid;
        if (idx < PRED_ELEM8) {
            const size_t e = (size_t)idx * 8;
            const f32x4 x = *reinterpret_cast<const f32x4*>(pred + e);
            const f32x4 y = *reinterpret_cast<const f32x4*>(pred + e + 4);
            short8 s;
            s[0]=f2bf(x[0]); s[1]=f2bf(x[1]); s[2]=f2bf(x[2]); s[3]=f2bf(x[3]);
            s[4]=f2bf(y[0]); s[5]=f2bf(y[1]); s[6]=f2bf(y[2]); s[7]=f2bf(y[3]);
            *reinterpret_cast<short8*>(pred_bf + e) = s;
        }
    }
}

// ---------------------------------------------------------------------------
// GEMM: O = bf16(Abf @ Wt[:, kofs:kofs+640] (+bias)).  Pure bf16 MFMA.
// Block = 256 thr (4 waves 2x2), block tile 64x64, wave tile 32x32.
// ---------------------------------------------------------------------------
__global__ __launch_bounds__(256) void gemm_kernel(
    const short* __restrict__ Abf, const short* __restrict__ Wt,
    const float* __restrict__ bias, short* __restrict__ O,
    int M, int kofs)
{
    const int rb   = blockIdx.x >> 4;
    const int cb   = blockIdx.x & 15;
    const int wid  = threadIdx.x >> 6;
    const int lane = threadIdx.x & 63;
    const int wr   = wid >> 1, wc = wid & 1;
    const int m    = lane & 15, g = lane >> 4;

    const int row0 = rb * 64 + wr * 32;
    const int col0 = cb * 64 + wc * 32;

    f32x4 z4; z4[0]=z4[1]=z4[2]=z4[3]=0.f;
    f32x4 acc00 = z4, acc01 = z4, acc10 = z4, acc11 = z4;

    const bool v0 = (row0 + m) < M;
    const bool v1 = (row0 + 16 + m) < M;
    const short* a0p = Abf + (size_t)(row0 + m) * DK;
    const short* a1p = Abf + (size_t)(row0 + 16 + m) * DK;
    const short* b0p = Wt + (size_t)(col0 + m) * KTOT + kofs;
    const short* b1p = Wt + (size_t)(col0 + 16 + m) * KTOT + kofs;

    short8 zero8;
    #pragma unroll
    for (int j = 0; j < 8; ++j) zero8[j] = 0;

    #pragma unroll 2
    for (int kk = 0; kk < DK; kk += 32) {
        const int k0 = kk + g * 8;
        const short8 a0 = v0 ? *reinterpret_cast<const short8*>(a0p + k0) : zero8;
        const short8 a1 = v1 ? *reinterpret_cast<const short8*>(a1p + k0) : zero8;
        const short8 b0 = *reinterpret_cast<const short8*>(b0p + k0);
        const short8 b1 = *reinterpret_cast<const short8*>(b1p + k0);
        acc00 = __builtin_amdgcn_mfma_f32_16x16x32_bf16(a0, b0, acc00, 0, 0, 0);
        acc01 = __builtin_amdgcn_mfma_f32_16x16x32_bf16(a0, b1, acc01, 0, 0, 0);
        acc10 = __builtin_amdgcn_mfma_f32_16x16x32_bf16(a1, b0, acc10, 0, 0, 0);
        acc11 = __builtin_amdgcn_mfma_f32_16x16x32_bf16(a1, b1, acc11, 0, 0, 0);
    }

    #pragma unroll
    for (int nt = 0; nt < 2; ++nt) {
        const int col = col0 + nt * 16 + m;
        const float bv = bias ? bias[col] : 0.f;
        #pragma unroll
        for (int mt = 0; mt < 2; ++mt) {
            const f32x4 a = nt ? (mt ? acc11 : acc01) : (mt ? acc10 : acc00);
            #pragma unroll
            for (int q = 0; q < 4; ++q) {
                const int row = row0 + mt * 16 + g * 4 + q;
                if (row < M)
                    O[(size_t)row * V + col] = f2bf(a[q] + bv);
            }
        }
    }
}

// ---------------------------------------------------------------------------
// out[bt][u][v] = enc_proj[bt][v] + pred_proj[b][u][v]  (bf16 in, f32 out)
// R12 A/B: REGULAR stores (was nontemporal) — fill kernels sustain 6.6 TB/s
// with the temporal/write-back path; nt measured ~4.8 TB/s effective.
// Everything else identical to R11.
// ---------------------------------------------------------------------------
__global__ __launch_bounds__(256) void bcast_kernel(
    const short* __restrict__ enc_proj, const short* __restrict__ pred_proj,
    float* __restrict__ out)
{
    const int bt0 = blockIdx.x * 2;
    const int b   = bt0 >> 8;            // T = 256
    const int tid = threadIdx.x;

    const f32x4 e0 = bf4_to_f32(*reinterpret_cast<const u16x4*>(
        enc_proj + (size_t)bt0 * V + tid * 4));
    const f32x4 e1 = bf4_to_f32(*reinterpret_cast<const u16x4*>(
        enc_proj + (size_t)(bt0 + 1) * V + tid * 4));

    const short* p = pred_proj + (size_t)b * U1 * V + tid * 4;
    float* o0 = out + (size_t)bt0 * U1 * V;
    float* o1 = out + (size_t)(bt0 + 1) * U1 * V;

    for (int u0 = 0; u0 < 64; u0 += 8) {
        u16x4 pv[8];
        #pragma unroll
        for (int j = 0; j < 8; ++j)
            pv[j] = *reinterpret_cast<const u16x4*>(p + (size_t)(u0 + j) * V);
        #pragma unroll
        for (int j = 0; j < 8; ++j) {
            const f32x4 pf = bf4_to_f32(pv[j]);
            *(reinterpret_cast<f32x4*>(o0 + (size_t)(u0 + j) * V) + tid) = e0 + pf;
            *(reinterpret_cast<f32x4*>(o1 + (size_t)(u0 + j) * V) + tid) = e1 + pf;
        }
    }
    {   // tail u = 64
        const f32x4 pf = bf4_to_f32(
            *reinterpret_cast<const u16x4*>(p + (size_t)64 * V));
        *(reinterpret_cast<f32x4*>(o0 + (size_t)64 * V) + tid) = e0 + pf;
        *(reinterpret_cast<f32x4*>(o1 + (size_t)64 * V) + tid) = e1 + pf;
    }
}

extern "C" void kernel_launch(void* const* d_in, const int* in_sizes, int n_in,
                              void* d_out, int out_size, void* d_ws, size_t ws_size,
                              hipStream_t stream)
{
    const float* enc  = (const float*)d_in[0];   // (8,256,640)
    const float* pred = (const float*)d_in[1];   // (8,65,640)
    const float* W    = (const float*)d_in[2];   // (1280,1024)
    const float* bias = (const float*)d_in[3];   // (1024,)
    float* out = (float*)d_out;                  // (8,256,65,1024)

    // ws packing (peak 10.10 MB): [Wt][encbf/pred_proj][pred_bf][enc_proj]
    short* Wt        = (short*)d_ws;                          // V*KTOT
    short* enc_bf    = Wt + (size_t)V * KTOT;                 // M_ENC*DK
    short* pred_bf   = enc_bf + (size_t)M_ENC * DK;           // M_PRED*DK
    short* enc_proj  = pred_bf + (size_t)M_PRED * DK;         // M_ENC*V
    short* pred_proj = enc_bf;                                // M_PRED*V (reuse)

    prep_kernel<<<NB_WT + NB_ENCC + NB_PREDC, 256, 0, stream>>>(
        W, enc, pred, Wt, enc_bf, pred_bf);

    gemm_kernel<<<(M_ENC / 64) * 16, 256, 0, stream>>>(
        enc_bf, Wt, nullptr, enc_proj, M_ENC, 0);

    gemm_kernel<<<((M_PRED + 63) / 64) * 16, 256, 0, stream>>>(
        pred_bf, Wt, bias, pred_proj, M_PRED, DK);

    bcast_kernel<<<M_ENC / 2, 256, 0, stream>>>(enc_proj, pred_proj, out);
}